// Round 5
// baseline (180.972 us; speedup 1.0000x reference)
//
#include <hip/hip_runtime.h>
#include <hip/hip_bf16.h>
#include <math.h>

#define B_ 4
#define S_ 2048
#define NH_ 16
#define DH_ 64
#define DM_ 1024

typedef __attribute__((ext_vector_type(4))) float f32x4;
typedef __attribute__((ext_vector_type(8))) short s16x8;
typedef __attribute__((ext_vector_type(4))) short s16x4;
typedef __attribute__((ext_vector_type(2))) unsigned u32x2;

static __device__ __forceinline__ short f2bf(float f) {
  union { float f; unsigned u; } c; c.f = f;
  unsigned r = c.u + 0x7fffu + ((c.u >> 16) & 1u);
  return (short)(r >> 16);
}

static __device__ __forceinline__ unsigned pkbf(float a, float b) {
  union { __hip_bfloat162 h; unsigned u; } cv;
  cv.h = __float22bfloat162_rn(make_float2(a, b));
  return cv.u;
}

static __device__ __forceinline__ s16x4 mk4(unsigned lo, unsigned hi) {
  union { unsigned u[2]; s16x4 v; } x; x.u[0] = lo; x.u[1] = hi; return x.v;
}

#if __has_builtin(__builtin_amdgcn_mfma_f32_16x16x16bf16_1k)
#define HAVE16 1
static __device__ __forceinline__ f32x4 pv_mfma(s16x4 a, s16x4 b, f32x4 c) {
  return __builtin_amdgcn_mfma_f32_16x16x16bf16_1k(a, b, c, 0, 0, 0);
}
#else
#define HAVE16 0
static __device__ __forceinline__ f32x4 pv_mfma(s16x4 a, s16x4 b, f32x4 c) {
  asm volatile("v_mfma_f32_16x16x16_bf16 %0, %1, %2, %0" : "+v"(c) : "v"(a), "v"(b));
  return c;
}
#endif

static __device__ __forceinline__ void gload16(const void* g, void* l) {
  __builtin_amdgcn_global_load_lds(
      (const __attribute__((address_space(1))) void*)g,
      (__attribute__((address_space(3))) void*)l, 16, 0, 0);
}

// ---------- fp32 -> bf16 convert ----------
__global__ void cvt_kernel(const float* __restrict__ in, short* __restrict__ out) {
  int i = (blockIdx.x * 256 + threadIdx.x) * 8;
  f32x4 a = *(const f32x4*)(in + i);
  f32x4 b = *(const f32x4*)(in + i + 4);
  s16x8 o;
  o[0] = f2bf(a[0]); o[1] = f2bf(a[1]); o[2] = f2bf(a[2]); o[3] = f2bf(a[3]);
  o[4] = f2bf(b[0]); o[5] = f2bf(b[1]); o[6] = f2bf(b[2]); o[7] = f2bf(b[3]);
  *(s16x8*)(out + i) = o;
}

// ---------- transpose+convert: W[k][n] fp32 -> WT[n][k] bf16 ----------
__global__ void tcvt_kernel(const float* __restrict__ W, short* __restrict__ WT) {
  __shared__ float t[32][33];
  int tx = threadIdx.x & 31, ty = threadIdx.x >> 5;
  int bn = blockIdx.x * 32, bk = blockIdx.y * 32;
#pragma unroll
  for (int r = 0; r < 32; r += 8)
    t[ty + r][tx] = W[(size_t)(bk + ty + r) * DM_ + bn + tx];
  __syncthreads();
#pragma unroll
  for (int r = 0; r < 32; r += 8)
    WT[(size_t)(bn + ty + r) * DM_ + bk + tx] = f2bf(t[tx][ty + r]);
}

// ---------- bf16 GEMM: C[M][1024] = A[M][1024] * BT[1024][1024]^T ----------
template <int EPI>
__global__ __launch_bounds__(256, 2) void gemm_kernel(
    const short* __restrict__ A, const short* __restrict__ BT,
    void* __restrict__ Cout, const float* __restrict__ bias) {
  __shared__ short Al[128 * 64];
  __shared__ short Bl[128 * 64];
  const int tid = threadIdx.x;
  const int wid = tid >> 6, lane = tid & 63;
  const int l15 = lane & 15, l4 = lane >> 4;
  const int bm = blockIdx.y * 128, bn = blockIdx.x * 128;
  const int wm = (wid >> 1) * 64, wn = (wid & 1) * 64;
  f32x4 acc[4][4] = {};

  for (int kt = 0; kt < DM_; kt += 64) {
    __syncthreads();
#pragma unroll
    for (int j = 0; j < 4; ++j) {
      int s = j * 256 + tid;
      int row = s >> 3;
      int sl = (s & 7) ^ (row & 7);
      gload16(A + (size_t)(bm + row) * DM_ + kt + sl * 8, &Al[j * 2048 + wid * 512]);
    }
#pragma unroll
    for (int j = 0; j < 4; ++j) {
      int s = j * 256 + tid;
      int row = s >> 3;
      int sl = (s & 7) ^ (row & 7);
      gload16(BT + (size_t)(bn + row) * DM_ + kt + sl * 8, &Bl[j * 2048 + wid * 512]);
    }
    __syncthreads();
#pragma unroll
    for (int kk = 0; kk < 2; ++kk) {
      s16x8 af[4], bfr[4];
#pragma unroll
      for (int mi = 0; mi < 4; ++mi) {
        int row = wm + mi * 16 + l15;
        int sl = (kk * 4 + l4) ^ (row & 7);
        af[mi] = *(const s16x8*)&Al[row * 64 + sl * 8];
      }
#pragma unroll
      for (int ni = 0; ni < 4; ++ni) {
        int row = wn + ni * 16 + l15;
        int sl = (kk * 4 + l4) ^ (row & 7);
        bfr[ni] = *(const s16x8*)&Bl[row * 64 + sl * 8];
      }
#pragma unroll
      for (int mi = 0; mi < 4; ++mi)
#pragma unroll
        for (int ni = 0; ni < 4; ++ni)
          acc[mi][ni] = __builtin_amdgcn_mfma_f32_16x16x32_bf16(af[mi], bfr[ni], acc[mi][ni], 0, 0, 0);
    }
  }

  if (EPI == 0) {
    short* Q = (short*)Cout;
#pragma unroll
    for (int mi = 0; mi < 4; ++mi)
#pragma unroll
      for (int ni = 0; ni < 4; ++ni)
#pragma unroll
        for (int r = 0; r < 4; ++r) {
          int rr = bm + wm + mi * 16 + l4 * 4 + r;
          int cc = bn + wn + ni * 16 + l15;
          int b = rr >> 11, s = rr & 2047, h = cc >> 6, d = cc & 63;
          Q[(((size_t)(b * NH_ + h) * S_ + s) << 6) + d] = f2bf(acc[mi][ni][r]);
        }
  } else {
    float* O = (float*)Cout;
#pragma unroll
    for (int mi = 0; mi < 4; ++mi)
#pragma unroll
      for (int ni = 0; ni < 4; ++ni)
#pragma unroll
        for (int r = 0; r < 4; ++r) {
          int rr = bm + wm + mi * 16 + l4 * 4 + r;
          int cc = bn + wn + ni * 16 + l15;
          O[(size_t)rr * DM_ + cc] = acc[mi][ni][r] + bias[cc];
        }
  }
}

// ---------- causal flash attention, Q=K=V from Qb [bh][s][64] bf16 ----------
// Paired q-tiles {p, 15-p} per block (uniform work). Kl: row-major XOR-swizzled
// (QK^T b128 reads, proven conflict-free). Vt: [d][sigma(kv)] with octet XOR
// swizzle; sigma(kv)=((kv>>2)&3)*16+(kv>>4)*4+(kv&3) makes one b128 read yield
// the 16x16x16 PV A-fragments for ki=2m and 2m+1 at quad l4 (conflict-free).
__global__ __launch_bounds__(256, 2) void attn_kernel(
    const short* __restrict__ Qb, short* __restrict__ Ctx) {
  __shared__ short Kl[2][64 * 64];
  __shared__ short Vt[2][64 * 64];
  const int tid = threadIdx.x;
  const int wid = tid >> 6, lane = tid & 63;
  const int l15 = lane & 15, l4 = lane >> 4;
  const int p = blockIdx.x >> 6;          // 0..7 pair index
  const int bh = blockIdx.x & 63;         // same-head blocks adjacent
  const int qtb = 15 - p;
  const short* Qh = Qb + (size_t)bh * S_ * DH_;
  const int q0a = p * 128 + wid * 32;
  const int q0b = qtb * 128 + wid * 32;
  const float C = 0.18033688068f;         // 0.125 * log2(e)

  const int u = tid & 7;
  const int kvA = tid >> 3;               // 0..31
  const int kvB = kvA + 32;

  // Q fragments for both q-sets (B-operand of S^T)
  s16x8 aqa[2][2], aqb[2][2];
#pragma unroll
  for (int qi = 0; qi < 2; ++qi)
#pragma unroll
    for (int kk = 0; kk < 2; ++kk) {
      aqa[qi][kk] = *(const s16x8*)(Qh + (size_t)(q0a + qi * 16 + l15) * DH_ + kk * 32 + l4 * 8);
      aqb[qi][kk] = *(const s16x8*)(Qh + (size_t)(q0b + qi * 16 + l15) * DH_ + kk * 32 + l4 * 8);
    }

  f32x4 oa[4][2] = {}, ob[4][2] = {};
  float ma[2] = {-INFINITY, -INFINITY}, la[2] = {0.f, 0.f}, mca[2] = {0.f, 0.f};
  float mb[2] = {-INFINITY, -INFINITY}, lb[2] = {0.f, 0.f}, mcb[2] = {0.f, 0.f};

  const int scA = ((kvA >> 2) & 3) * 16 + ((kvA >> 4) << 2) + (kvA & 3);
  const int scB = ((kvB >> 2) & 3) * 16 + ((kvB >> 4) << 2) + (kvB & 3);

  auto stage = [&](int c, s16x8 a, s16x8 b) {
    int g7 = kvA & 7;                     // == kvB & 7
    *(s16x8*)&Kl[c][kvA * 64 + ((u ^ g7) << 3)] = a;
    *(s16x8*)&Kl[c][kvB * 64 + ((u ^ g7) << 3)] = b;
    int oA = scA >> 3, wA = scA & 7;
    int oB = scB >> 3, wB = scB & 7;
#pragma unroll
    for (int i = 0; i < 8; ++i) {
      int ii = i ^ u;                     // stagger; dr & 7 == ii
      int dr = u * 8 + ii;
      Vt[c][dr * 64 + ((oA ^ ii) << 3) + wA] = a[ii];
      Vt[c][dr * 64 + ((oB ^ ii) << 3) + wB] = b[ii];
    }
  };

  {
    s16x8 a = *(const s16x8*)(Qh + (size_t)kvA * DH_ + u * 8);
    s16x8 b = *(const s16x8*)(Qh + (size_t)kvB * DH_ + u * 8);
    stage(0, a, b);
  }

  // QK^T + online softmax for one q-set; leaves packed P (bf16 pairs) in pw
  auto qksoft = [&](const s16x8 (&aq)[2][2], int q0, f32x4 (&acc)[4][2],
                    float (&mr)[2], float (&lr)[2], float (&mc)[2],
                    unsigned (&pw)[4][2][2], int kv0, const short* kl) {
    f32x4 sa[4][2] = {};
#pragma unroll
    for (int kk = 0; kk < 2; ++kk) {
      s16x8 ka[4];
#pragma unroll
      for (int ki = 0; ki < 4; ++ki) {
        int row = ki * 16 + l15;
        ka[ki] = *(const s16x8*)&kl[row * 64 + (((kk * 4 + l4) ^ (row & 7)) << 3)];
      }
#pragma unroll
      for (int ki = 0; ki < 4; ++ki)
#pragma unroll
        for (int qi = 0; qi < 2; ++qi)
          sa[ki][qi] = __builtin_amdgcn_mfma_f32_16x16x32_bf16(ka[ki], aq[qi][kk], sa[ki][qi], 0, 0, 0);
    }
    if (kv0 + 63 > q0) {                  // boundary: causal mask
#pragma unroll
      for (int ki = 0; ki < 4; ++ki)
#pragma unroll
        for (int qi = 0; qi < 2; ++qi)
#pragma unroll
          for (int r = 0; r < 4; ++r) {
            int kvg = kv0 + ki * 16 + l4 * 4 + r;
            int qg = q0 + qi * 16 + l15;
            if (kvg > qg) sa[ki][qi][r] = -INFINITY;
          }
    }
    float pm[2];
#pragma unroll
    for (int qi = 0; qi < 2; ++qi) {
      float m0 = fmaxf(fmaxf(sa[0][qi][0], sa[0][qi][1]), fmaxf(sa[0][qi][2], sa[0][qi][3]));
      float m1 = fmaxf(fmaxf(sa[1][qi][0], sa[1][qi][1]), fmaxf(sa[1][qi][2], sa[1][qi][3]));
      float m2 = fmaxf(fmaxf(sa[2][qi][0], sa[2][qi][1]), fmaxf(sa[2][qi][2], sa[2][qi][3]));
      float m3 = fmaxf(fmaxf(sa[3][qi][0], sa[3][qi][1]), fmaxf(sa[3][qi][2], sa[3][qi][3]));
      float m = fmaxf(fmaxf(m0, m1), fmaxf(m2, m3));
      m = fmaxf(m, __shfl_xor(m, 16, 64));
      m = fmaxf(m, __shfl_xor(m, 32, 64));
      pm[qi] = m;
    }
    float need = fmaxf(pm[0] - mr[0], pm[1] - mr[1]);
    if (!__all(need <= 44.f)) {           // defer-max (T13)
      float fac[2];
#pragma unroll
      for (int qi = 0; qi < 2; ++qi) {
        float mn = fmaxf(mr[qi], pm[qi]);
        fac[qi] = exp2f((mr[qi] - mn) * C);
        mr[qi] = mn;
        mc[qi] = mn * C;
        lr[qi] *= fac[qi];
      }
#pragma unroll
      for (int df = 0; df < 4; ++df)
#pragma unroll
        for (int qi = 0; qi < 2; ++qi)
#pragma unroll
          for (int r = 0; r < 4; ++r)
            acc[df][qi][r] *= fac[qi];
    }
    float srow[2] = {0.f, 0.f};
#pragma unroll
    for (int ki = 0; ki < 4; ++ki)
#pragma unroll
      for (int qi = 0; qi < 2; ++qi) {
        float e0 = exp2f(fmaf(sa[ki][qi][0], C, -mc[qi]));
        float e1 = exp2f(fmaf(sa[ki][qi][1], C, -mc[qi]));
        float e2 = exp2f(fmaf(sa[ki][qi][2], C, -mc[qi]));
        float e3 = exp2f(fmaf(sa[ki][qi][3], C, -mc[qi]));
        srow[qi] += (e0 + e1) + (e2 + e3);
        pw[ki][qi][0] = pkbf(e0, e1);
        pw[ki][qi][1] = pkbf(e2, e3);
      }
#pragma unroll
    for (int qi = 0; qi < 2; ++qi) {
      float s = srow[qi];
      s += __shfl_xor(s, 16, 64);
      s += __shfl_xor(s, 32, 64);
      lr[qi] += s;
    }
  };

  int c = 0;
  const int nt = 2 * qtb + 2;
  for (int t = 0; t < nt; ++t) {
    __syncthreads();                      // publish buf c
    const int kv0 = t * 64;
    const bool nx = (t + 1 < nt);
    s16x8 na, nb;
    if (nx) {                             // issue next tile's loads early (T14)
      int kb = kv0 + 64;
      na = *(const s16x8*)(Qh + (size_t)(kb + kvA) * DH_ + u * 8);
      nb = *(const s16x8*)(Qh + (size_t)(kb + kvB) * DH_ + u * 8);
    }

    const bool doB = (kv0 <= q0b);
    const bool doA = (kv0 <= q0a);
    if (doB) {
      const short* kl = &Kl[c][0];
      const short* vt = &Vt[c][0];
      unsigned pwa[4][2][2], pwb[4][2][2];
      qksoft(aqb, q0b, ob, mb, lb, mcb, pwb, kv0, kl);
      if (doA) qksoft(aqa, q0a, oa, ma, la, mca, pwa, kv0, kl);

      // O^T += V^T P for both sets, sharing the Vt b128 reads
#pragma unroll
      for (int df = 0; df < 4; ++df) {
        int dr = df * 16 + l15;
#pragma unroll
        for (int m = 0; m < 2; ++m) {
          s16x8 v8 = *(const s16x8*)&vt[dr * 64 + ((((l4 << 1) + m) ^ (dr & 7)) << 3)];
          s16x4 lo = __builtin_shufflevector(v8, v8, 0, 1, 2, 3);   // ki = 2m
          s16x4 hi = __builtin_shufflevector(v8, v8, 4, 5, 6, 7);   // ki = 2m+1
          int k0 = 2 * m, k1 = 2 * m + 1;
          ob[df][0] = pv_mfma(lo, mk4(pwb[k0][0][0], pwb[k0][0][1]), ob[df][0]);
          ob[df][1] = pv_mfma(lo, mk4(pwb[k0][1][0], pwb[k0][1][1]), ob[df][1]);
          ob[df][0] = pv_mfma(hi, mk4(pwb[k1][0][0], pwb[k1][0][1]), ob[df][0]);
          ob[df][1] = pv_mfma(hi, mk4(pwb[k1][1][0], pwb[k1][1][1]), ob[df][1]);
          if (doA) {
            oa[df][0] = pv_mfma(lo, mk4(pwa[k0][0][0], pwa[k0][0][1]), oa[df][0]);
            oa[df][1] = pv_mfma(lo, mk4(pwa[k0][1][0], pwa[k0][1][1]), oa[df][1]);
            oa[df][0] = pv_mfma(hi, mk4(pwa[k1][0][0], pwa[k1][0][1]), oa[df][0]);
            oa[df][1] = pv_mfma(hi, mk4(pwa[k1][1][0], pwa[k1][1][1]), oa[df][1]);
          }
        }
      }
#if !HAVE16
      asm volatile("s_nop 7" :::);
      asm volatile("s_nop 7" :::);
#endif
    }

    if (nx) stage(c ^ 1, na, nb);
    c ^= 1;
  }

  const int b = bh >> 4, h = bh & 15;
  auto wout = [&](f32x4 (&o)[4][2], float (&lr)[2], int q0) {
    float inv[2] = {1.f / lr[0], 1.f / lr[1]};
#pragma unroll
    for (int df = 0; df < 4; ++df)
#pragma unroll
      for (int qi = 0; qi < 2; ++qi) {
        int qg = q0 + qi * 16 + l15;
        int col = h * 64 + df * 16 + l4 * 4;
        u32x2 pk;
        pk[0] = pkbf(o[df][qi][0] * inv[qi], o[df][qi][1] * inv[qi]);
        pk[1] = pkbf(o[df][qi][2] * inv[qi], o[df][qi][3] * inv[qi]);
        *(u32x2*)&Ctx[(size_t)(b * S_ + qg) * DM_ + col] = pk;
      }
  };
  wout(ob, lb, q0b);
  wout(oa, la, q0a);
}

extern "C" void kernel_launch(void* const* d_in, const int* in_sizes, int n_in,
                              void* d_out, int out_size, void* d_ws, size_t ws_size,
                              hipStream_t stream) {
  const float* x  = (const float*)d_in[0];
  const float* Wq = (const float*)d_in[1];
  const float* Wo = (const float*)d_in[2];
  const float* bo = (const float*)d_in[3];
  float* out = (float*)d_out;
  char* ws = (char*)d_ws;

  short* xb  = (short*)(ws);
  short* WqT = (short*)(ws + 16777216);
  short* WoT = (short*)(ws + 18874368);
  short* Qb  = (short*)(ws + 20971520);
  short* Ctx = xb;  // alias: x dead after GEMM1

  cvt_kernel<<<4096, 256, 0, stream>>>(x, xb);
  tcvt_kernel<<<dim3(32, 32), 256, 0, stream>>>(Wq, WqT);
  tcvt_kernel<<<dim3(32, 32), 256, 0, stream>>>(Wo, WoT);
  gemm_kernel<0><<<dim3(8, 64), 256, 0, stream>>>(xb, WqT, Qb, nullptr);
  attn_kernel<<<512, 256, 0, stream>>>(Qb, Ctx);
  gemm_kernel<1><<<dim3(8, 64), 256, 0, stream>>>(Ctx, WoT, out, bo);
}